// Round 4
// baseline (1014.345 us; speedup 1.0000x reference)
//
#include <hip/hip_runtime.h>
#include <hip/hip_bf16.h>
#include <math.h>

#define HW 64
#define NPIX 4096
#define NB 16
#define NCH 1792
#define PW 72                 // padded width (units of 8ch)
#define PROWS 70              // padded rows (64 + 2*3 halo)
#define PLANE (PROWS * PW)    // 5040 units per 8-ch plane

typedef __bf16 bf16;
typedef __bf16 bf16x8 __attribute__((ext_vector_type(8)));
typedef float f32x4 __attribute__((ext_vector_type(4)));

struct PtrQuad { const float* p[4]; };

// repacked-weight sizes (bf16 elements), per branch: [w3 | w5 | w7]
constexpr size_t W3SZ = 9 * 1 * 64 * 32;
constexpr size_t W5SZ = 25 * 3 * 128 * 32;
constexpr size_t W7SZ = 49 * 5 * 256 * 32;
constexpr size_t WBR  = W3SZ + W5SZ + W7SZ;
constexpr size_t PLE  = (size_t)PLANE * 8;     // bf16 elements per plane

// ---------------------------------------------------------------------------
__global__ __launch_bounds__(256) void init_kernel(float* __restrict__ gap_sum,
                                                   float* __restrict__ dct_sum,
                                                   float* __restrict__ dctw) {
    int tid = blockIdx.x * 256 + threadIdx.x;
    if (tid < NB * NCH) { gap_sum[tid] = 0.f; dct_sum[tid] = 0.f; }
    if (blockIdx.x == 0 && threadIdx.x < HW) {
        int i = threadIdx.x;
        float s = 0.f;
        for (int u = 0; u < 5; ++u) {
            float scale = (u == 0) ? 0.125f : 0.17677669529663687f;
            s += cosf(3.14159265358979323846f * (2.f * i + 1.f) * u / 128.f) * scale;
        }
        dctw[i] = s * 0.2f;
    }
}

// grid-stride zero of bf16 scratch (16B granules)
__global__ __launch_bounds__(256) void zero_kernel(float4* __restrict__ p, long n) {
    long i = (long)blockIdx.x * 256 + threadIdx.x;
    long stride = (long)gridDim.x * 256;
    for (; i < n; i += stride) p[i] = float4{0.f, 0.f, 0.f, 0.f};
}

// x (fp32 NCHW) -> padded planar-8: xp[b][g][4 planes][PLANE][8]; only plane 0
// ch 0..2 are real, rest stays zero (zero_kernel ran before).
__global__ __launch_bounds__(256) void prep_x_kernel(const float* __restrict__ x,
                                                     bf16* __restrict__ xp) {
    int tid = blockIdx.x * 256 + threadIdx.x;      // NB*2*NPIX
    if (tid >= NB * 2 * NPIX) return;
    int pix = tid & (NPIX - 1);
    int g = (tid >> 12) & 1;
    int b = tid >> 13;
    int h = pix >> 6, w = pix & 63;
    size_t base = ((size_t)(b * 2 + g) * 4) * PLE + ((size_t)(h + 3) * PW + (w + 3)) * 8;
    for (int c = 0; c < 3; ++c)
        xp[base + c] = (bf16)x[((size_t)(b * 6 + g * 3 + c)) * NPIX + pix];
}

// weight repack: fp32 [COUT][CIN][K][K] -> bf16 [K*K][CHUNKS][COUT][32]
template <int K, int CHUNKS, int CIN_ACT, int COUT>
__global__ __launch_bounds__(256) void prep_w_all(PtrQuad src, bf16* __restrict__ dst) {
    constexpr int CIN = CIN_ACT + 3;
    constexpr int TOT = K * K * CHUNKS * COUT * 32;
    int tid = blockIdx.x * 256 + threadIdx.x;
    if (tid >= 4 * TOT) return;
    int br = tid / TOT;
    int idx = tid - br * TOT;
    int cc = idx & 31;
    int co = (idx >> 5) % COUT;
    int rest = idx / (32 * COUT);
    int chunk = rest % CHUNKS;
    int ks = rest / CHUNKS;
    int ky = ks / K, kx = ks % K;
    int ci;
    if (chunk < CHUNKS - 1) ci = chunk * 32 + cc;
    else ci = (cc < 3) ? (CIN_ACT + cc) : -1;
    const float* w = src.p[br];
    float v = (ci >= 0) ? w[(((size_t)co * CIN + ci) * K + ky) * K + kx] : 0.f;
    dst[(size_t)br * WBR + idx] = (bf16)v;
}

// ---------------------------------------------------------------------------
// Implicit-GEMM conv, MFMA 16x16x32 bf16, async-DMA double-buffered K-loop.
// Block 512 thr = 8 waves (4 m-groups x 2 n-groups). Block tile: 8 rows x 64
// cols x NBLK couts. Grid (8, COUT/NBLK, NB*nbr). 1 block/CU (big LDS dbuf).
// Staging: wave w DMAs kseg (w>>1), row-half (w&1) straight from the padded
// planar global layout — contiguous, no bounds checks, no VGPR round-trip.
// Pipeline: issue chunk c+1 -> other buffer, s_waitcnt vmcnt(NI) (keeps c+1
// in flight), raw s_barrier, compute chunk c. (m139-style raw-barrier loop.)
// ---------------------------------------------------------------------------
template <int K, int CHUNKS, int COUT, int NBLK, bool STORE>
__global__ __launch_bounds__(512, 2) void conv_mfma(
    const bf16* __restrict__ act_in,   // [lbr*NB+b][(CHUNKS-1)*4 planes][PLANE][8]
    const bf16* __restrict__ xpad,     // [b][g][4 planes][PLANE][8]
    const bf16* __restrict__ wall, size_t stage_woff,
    PtrQuad biasq,
    bf16* __restrict__ act_out,        // [lbr*NB+b][COUT/8 planes][PLANE][8]
    float* __restrict__ gap_sum, float* __restrict__ dct_sum,
    int stage_coff, const float* __restrict__ dctw, int br0)
{
    constexpr int PAD = K / 2;
    constexpr int COFF = 3 - PAD;          // layout pad (3) minus conv pad
    constexpr int HR = 8 + K - 1;          // staged rows (R=8)
    constexpr int RH = HR / 2;             // rows per staging wave
    constexpr int UN = RH * PW;            // 16B units per staging wave
    constexpr int NI = (UN + 63) / 64;     // DMA instructions per wave
    constexpr int BUFU = 4 * HR * PW;      // units per buffer
    constexpr int ACT_CHUNKS = CHUNKS - 1;
    constexpr int WN = NBLK / 32;          // n-tiles per wave
    constexpr int CW = CHUNKS * COUT * 32; // wrep elements per tap
    constexpr int OPL = COUT / 8;          // output planes

    __shared__ __align__(16) bf16 s_in[2 * BUFU * 8];

    const int tid = threadIdx.x;
    const int lane = tid & 63;
    const int wv = tid >> 6;
    const int wavem = wv >> 1;             // 0..3: rows wavem*2..+1
    const int wn = wv & 1;
    const int q = lane >> 4;
    const int ln = lane & 15;
    const int sseg = wv >> 1;              // staging kseg
    const int shalf = wv & 1;              // staging row-half

    const int bz = blockIdx.z;
    const int b = bz & 15;
    const int lbr = bz >> 4;
    const int br = br0 + lbr;
    const int g = br >> 1;

    const int o0 = blockIdx.x * 8;
    const int prow0 = o0 + COFF;           // first staged padded row
    const int n0 = blockIdx.y * NBLK + wn * (NBLK / 2);

    const bf16* wrep = wall + (size_t)br * WBR + stage_woff;
    const float* bias = biasq.p[br];
    const size_t img = (size_t)(lbr * NB + b);

    int abase[8];
#pragma unroll
    for (int t = 0; t < 8; ++t) {
        int lr = wavem * 2 + (t >> 2);
        int ct = (t & 3) * 16;
        abase[t] = ((q * HR + lr) * PW + ct + ln + COFF) * 8;
    }

    f32x4 acc[8][WN];
#pragma unroll
    for (int t = 0; t < 8; ++t)
#pragma unroll
        for (int u = 0; u < WN; ++u) acc[t][u] = f32x4{0.f, 0.f, 0.f, 0.f};

    auto issue = [&](int chunk, int sel) {
        const bf16* pl;
        if (chunk < ACT_CHUNKS)
            pl = act_in + (img * (ACT_CHUNKS * 4) + chunk * 4 + sseg) * PLE;
        else
            pl = xpad + ((size_t)((b * 2 + g) * 4 + sseg)) * PLE;
        const bf16* gb = pl + (size_t)(prow0 + shalf * RH) * PW * 8;
        const bf16* lb = s_in + ((size_t)sel * BUFU + (sseg * HR + shalf * RH) * PW) * 8;
#pragma unroll
        for (int i = 0; i < NI; ++i) {
            int u = i * 64 + lane;
            if (u < UN)
                __builtin_amdgcn_global_load_lds(
                    (const __attribute__((address_space(1))) void*)(gb + (size_t)u * 8),
                    (__attribute__((address_space(3))) void*)(lb + i * 512),
                    16, 0, 0);
        }
    };

    auto compute = [&](int chunk, int sel) {
        const bf16* buf = s_in + (size_t)sel * BUFU * 8;
        const bf16* wchunk = wrep + ((size_t)chunk * COUT + n0) * 32 + ln * 32 + q * 8;
#pragma unroll 1
        for (int ky = 0; ky < K; ++ky) {
            const bf16* wky = wchunk + (size_t)(ky * K) * CW;
            const int kyoff = ky * PW * 8;
#pragma unroll
            for (int kx = 0; kx < K; ++kx) {
                const bf16* wstep = wky + (size_t)kx * CW;
                bf16x8 bfr[WN];
#pragma unroll
                for (int u = 0; u < WN; ++u)
                    bfr[u] = *(const bf16x8*)(wstep + u * 512);
                const int koff = kyoff + kx * 8;
                bf16x8 afr[8];
#pragma unroll
                for (int t = 0; t < 8; ++t)
                    afr[t] = *(const bf16x8*)(buf + abase[t] + koff);
#pragma unroll
                for (int t = 0; t < 8; ++t)
#pragma unroll
                    for (int u = 0; u < WN; ++u)
                        acc[t][u] = __builtin_amdgcn_mfma_f32_16x16x32_bf16(
                            afr[t], bfr[u], acc[t][u], 0, 0, 0);
            }
        }
    };

    issue(0, 0);
#pragma unroll 1
    for (int c = 0; c < CHUNKS - 1; ++c) {
        issue(c + 1, (c + 1) & 1);                     // prefetch, stays in flight
        __builtin_amdgcn_s_waitcnt(0xF70 | NI);        // drain chunk c only
        __builtin_amdgcn_s_barrier();                  // all waves' DMAs landed
        compute(c, c & 1);
        __builtin_amdgcn_s_barrier();                  // buffer free for reuse
    }
    __builtin_amdgcn_s_waitcnt(0xF70);                 // vmcnt(0): last chunk
    __builtin_amdgcn_s_barrier();
    compute(CHUNKS - 1, (CHUNKS - 1) & 1);

    // ---- epilogue: bias + relu (+store) + gap/dct reduction ----
    float gsum[WN], dsum[WN], bv[WN];
#pragma unroll
    for (int u = 0; u < WN; ++u) {
        gsum[u] = 0.f; dsum[u] = 0.f;
        bv[u] = bias[n0 + u * 16 + ln];
    }

#pragma unroll
    for (int t = 0; t < 8; ++t) {
        const int lr = wavem * 2 + (t >> 2);
        const int gr = o0 + lr;
        const float wrow = dctw[gr];
        const int ct = (t & 3) * 16;
#pragma unroll
        for (int r = 0; r < 4; ++r) {
            const int gc = ct + q * 4 + r;
            const float wcd = dctw[gc] * wrow;
#pragma unroll
            for (int u = 0; u < WN; ++u) {
                float v = fmaxf(acc[t][u][r] + bv[u], 0.f);
                if constexpr (STORE) {
                    int ch = n0 + u * 16 + ln;
                    act_out[(img * OPL + (ch >> 3)) * PLE +
                            ((size_t)(gr + 3) * PW + (gc + 3)) * 8 + (ch & 7)] = (bf16)v;
                }
                gsum[u] += v;
                dsum[u] = fmaf(v, wcd, dsum[u]);
            }
        }
    }

    const int cb = br * 448 + stage_coff;
#pragma unroll
    for (int u = 0; u < WN; ++u) {
        float gv = gsum[u], dv = dsum[u];
        gv += __shfl_xor(gv, 16, 64); gv += __shfl_xor(gv, 32, 64);
        dv += __shfl_xor(dv, 16, 64); dv += __shfl_xor(dv, 32, 64);
        if (q == 0) {
            int ch = cb + n0 + u * 16 + ln;
            atomicAdd(&gap_sum[b * NCH + ch], gv);
            atomicAdd(&dct_sum[b * NCH + ch], dv);
        }
    }
}

// ---------------------------------------------------------------------------
__global__ __launch_bounds__(256) void head_kernel(
    const float* __restrict__ gap_sum, const float* __restrict__ dct_sum,
    const float* __restrict__ gap_w, const float* __restrict__ gap_b,
    const float* __restrict__ dct_w, const float* __restrict__ dct_b,
    const float* __restrict__ gamma, const float* __restrict__ beta,
    const float* __restrict__ mean, const float* __restrict__ var,
    float* __restrict__ out)
{
    const int blk = blockIdx.x;
    const int b = blk / 24;
    const int rem = blk - b * 24;
    const int kind = rem / 12;
    const int i = rem - kind * 12;
    const int tid = threadIdx.x;

    float partial = 0.f;
    if (kind == 0) {
        for (int cc = tid; cc < NCH; cc += 256)
            partial += gap_sum[b * NCH + cc] * (1.f / 4096.f) * gap_w[i * NCH + cc];
    } else {
        for (int cc = tid; cc < NCH; cc += 256) {
            float f = dct_sum[b * NCH + cc];
            f = gamma[cc] * (f - mean[cc]) * rsqrtf(var[cc] + 1e-5f) + beta[cc];
            partial += f * dct_w[i * NCH + cc];
        }
    }
#pragma unroll
    for (int off = 32; off > 0; off >>= 1) partial += __shfl_down(partial, off, 64);
    __shared__ float red[4];
    if ((tid & 63) == 0) red[tid >> 6] = partial;
    __syncthreads();
    if (tid == 0) {
        float tot = red[0] + red[1] + red[2] + red[3];
        tot += (kind == 0 ? gap_b[i] : dct_b[i]);
        out[kind * (NB * 12) + b * 12 + i] = tot;
    }
}

// ---------------------------------------------------------------------------
extern "C" void kernel_launch(void* const* d_in, const int* in_sizes, int n_in,
                              void* d_out, int out_size, void* d_ws, size_t ws_size,
                              hipStream_t stream)
{
    const float* x = (const float*)d_in[0];

    float* fws = (float*)d_ws;
    float* dctw    = fws;                      // 64
    float* gap_sum = fws + 64;                 // 16*1792
    float* dct_sum = gap_sum + NB * NCH;       // 16*1792
    bf16* bws = (bf16*)(dct_sum + NB * NCH);   // 229,632 B offset (16B aligned)

    const size_t WALL_E = 4 * WBR;                       // 9,330,688
    const size_t XP_E   = (size_t)NB * 2 * 4 * PLE;      // 5,160,960
    const size_t A3_BR  = (size_t)NB * 8 * PLE;          // 5,160,960 per branch
    const size_t A5_BR  = (size_t)NB * 16 * PLE;         // 10,321,920 per branch

    // pick branches-per-launch to fit ws
    const size_t fixed_b = 229632 + 2 * (WALL_E + XP_E);
    int nbr = 1;
    if (ws_size >= fixed_b + 2 * 4 * (A3_BR + A5_BR)) nbr = 4;
    else if (ws_size >= fixed_b + 2 * 2 * (A3_BR + A5_BR)) nbr = 2;

    bf16* wall = bws;
    bf16* xp   = wall + WALL_E;
    bf16* a3p  = xp + XP_E;
    bf16* a5p  = a3p + (size_t)nbr * A3_BR;

    hipLaunchKernelGGL(init_kernel, dim3((NB * NCH + 255) / 256), dim3(256), 0, stream,
                       gap_sum, dct_sum, dctw);

    const long zero16 = (long)((XP_E + (size_t)nbr * (A3_BR + A5_BR)) * 2 / 16);
    hipLaunchKernelGGL(zero_kernel, dim3(2048), dim3(256), 0, stream, (float4*)xp, zero16);

    hipLaunchKernelGGL(prep_x_kernel, dim3((NB * 2 * NPIX) / 256), dim3(256), 0, stream, x, xp);

    PtrQuad w3q = {{(const float*)d_in[1], (const float*)d_in[7], (const float*)d_in[13], (const float*)d_in[19]}};
    PtrQuad b3q = {{(const float*)d_in[2], (const float*)d_in[8], (const float*)d_in[14], (const float*)d_in[20]}};
    PtrQuad w5q = {{(const float*)d_in[3], (const float*)d_in[9], (const float*)d_in[15], (const float*)d_in[21]}};
    PtrQuad b5q = {{(const float*)d_in[4], (const float*)d_in[10], (const float*)d_in[16], (const float*)d_in[22]}};
    PtrQuad w7q = {{(const float*)d_in[5], (const float*)d_in[11], (const float*)d_in[17], (const float*)d_in[23]}};
    PtrQuad b7q = {{(const float*)d_in[6], (const float*)d_in[12], (const float*)d_in[18], (const float*)d_in[24]}};

    hipLaunchKernelGGL((prep_w_all<3, 1, 0, 64>), dim3((4 * W3SZ + 255) / 256), dim3(256), 0, stream, w3q, wall);
    hipLaunchKernelGGL((prep_w_all<5, 3, 64, 128>), dim3((4 * W5SZ + 255) / 256), dim3(256), 0, stream, w5q, wall + W3SZ);
    hipLaunchKernelGGL((prep_w_all<7, 5, 128, 256>), dim3((4 * W7SZ + 255) / 256), dim3(256), 0, stream, w7q, wall + W3SZ + W5SZ);

    for (int br0 = 0; br0 < 4; br0 += nbr) {
        hipLaunchKernelGGL((conv_mfma<3, 1, 64, 64, true>), dim3(8, 1, NB * nbr), dim3(512), 0, stream,
                           (const bf16*)nullptr, xp, wall, 0, b3q,
                           a3p, gap_sum, dct_sum, 0, dctw, br0);
        hipLaunchKernelGGL((conv_mfma<5, 3, 128, 128, true>), dim3(8, 1, NB * nbr), dim3(512), 0, stream,
                           a3p, xp, wall, W3SZ, b5q,
                           a5p, gap_sum, dct_sum, 64, dctw, br0);
        hipLaunchKernelGGL((conv_mfma<7, 5, 256, 128, false>), dim3(8, 2, NB * nbr), dim3(512), 0, stream,
                           a5p, xp, wall, W3SZ + W5SZ, b7q,
                           (bf16*)nullptr, gap_sum, dct_sum, 192, dctw, br0);
    }

    hipLaunchKernelGGL(head_kernel, dim3(NB * 24), dim3(256), 0, stream,
                       gap_sum, dct_sum,
                       (const float*)d_in[25], (const float*)d_in[26],
                       (const float*)d_in[27], (const float*)d_in[28],
                       (const float*)d_in[29], (const float*)d_in[30],
                       (const float*)d_in[31], (const float*)d_in[32],
                       (float*)d_out);
}